// Round 16
// baseline (42.356 us; speedup 1.0000x reference)
//
#include <hip/hip_runtime.h>
#include <math.h>
#include <stdint.h>

#define D_MODEL 128
#define EDGE_DIM 9
#define HIDDEN 256
#define BATCH 2
#define NN 512

typedef _Float16 h2v    __attribute__((ext_vector_type(2)));
typedef __fp16   fp16x2 __attribute__((ext_vector_type(2)));
typedef _Float16 f16x8  __attribute__((ext_vector_type(8)));
typedef float    f32x4  __attribute__((ext_vector_type(4)));

struct H8 { h2v v[4]; };   // 16B = one MFMA A/B fragment

__device__ __forceinline__ uint32_t h2u(h2v v) { return __builtin_bit_cast(uint32_t, v); }
__device__ __forceinline__ h2v u2h(uint32_t u) { return __builtin_bit_cast(h2v, u); }
__device__ __forceinline__ h2v pkrtz(float a, float b) {
    return __builtin_bit_cast(h2v, __builtin_amdgcn_cvt_pkrtz(a, b));
}
__device__ __forceinline__ h2v relu2(h2v v) {
    h2v z = {(_Float16)0.0f, (_Float16)0.0f};
    return __builtin_elementwise_max(v, z);
}
__device__ __forceinline__ float fdot2(h2v a, h2v b, float c) {
    return __builtin_amdgcn_fdot2(__builtin_bit_cast(fp16x2, a),
                                  __builtin_bit_cast(fp16x2, b), c, false);
}
__device__ __forceinline__ float sigmoidf_(float x) { return 1.f / (1.f + expf(-x)); }
// uint4 element by unroll-constant index (folds to .x/.y/.z/.w)
__device__ __forceinline__ uint32_t el(const uint4& u, int k) {
    switch (k) { case 0: return u.x; case 1: return u.y; case 2: return u.z; default: return u.w; }
}

// ---------------------------------------------------------------------------
// Kernel 1 (MFMA): C = z @ W for one of {Wo1, We_i, We_j} per block.y.
// (Unchanged from round 12: pj stored TRANSPOSED pj_T[hp][row].)
// ---------------------------------------------------------------------------
__global__ __launch_bounds__(512) void node_mfma_kernel(
    const float* __restrict__ z,      // (B*N, 128)
    const float* __restrict__ Wo1,    // (128,256)
    const float* __restrict__ bo1,    // (256)
    const float* __restrict__ Wo2,    // (256,1)
    const float* __restrict__ bo2,    // (1)
    const float* __restrict__ We_i,   // (128,256)
    const float* __restrict__ We_j,   // (128,256)
    const float* __restrict__ be1,    // (256)
    float* __restrict__ organ_out,    // (B*N)
    uint32_t* __restrict__ pi_h,      // (B*N,128) half2 rows, includes +be1
    uint32_t* __restrict__ pj_T)      // (128,B*N) half2 TRANSPOSED
{
    __shared__ uint32_t Wlds[256][68];     // ~69.6 KiB, f16-pair, [h][d2^swz]
    __shared__ float org_part[32][4];

    const int t    = threadIdx.x;
    const int lane = t & 63;
    const int wave = t >> 6;
    const int rb   = blockIdx.x;           // row-block: rows 32*rb..32*rb+31
    const int m    = blockIdx.y;           // 0 = Wo1/organ, 1 = We_i/pi, 2 = We_j/pj

    const float* __restrict__ W = (m == 0) ? Wo1 : (m == 1) ? We_i : We_j;

    // ---- stage W -> LDS f16, transposed, swizzled ----
    for (int idx = t; idx < 64 * 256; idx += 512) {
        const int d2 = idx >> 8;           // 0..63 (d-pair)
        const int h  = idx & 255;          // coalesced over h
        const float wlo = W[(2 * d2) * 256 + h];
        const float whi = W[(2 * d2 + 1) * 256 + h];
        Wlds[h][d2 ^ ((h & 7) << 3)] = h2u(pkrtz(wlo, whi));
    }

    // ---- A-frags straight from global ----
    const int rt = wave & 1;               // row-tile
    const int cg = wave >> 1;              // col-group (4 tiles of 16)
    const int kg = lane >> 4;              // k-subgroup
    const int row = rb * 32 + rt * 16 + (lane & 15);

    f16x8 A[4];
#pragma unroll
    for (int kt = 0; kt < 4; ++kt) {
        const float4 za = *(const float4*)&z[(size_t)row * 128 + kt * 32 + kg * 8];
        const float4 zb = *(const float4*)&z[(size_t)row * 128 + kt * 32 + kg * 8 + 4];
        H8 a;
        a.v[0] = pkrtz(za.x, za.y); a.v[1] = pkrtz(za.z, za.w);
        a.v[2] = pkrtz(zb.x, zb.y); a.v[3] = pkrtz(zb.z, zb.w);
        A[kt] = __builtin_bit_cast(f16x8, a);
    }

    __syncthreads();

    // ---- MFMA main: 4 col-tiles x 4 k-tiles ----
    f32x4 C[4];
#pragma unroll
    for (int ct = 0; ct < 4; ++ct) {
        const int col = (cg * 4 + ct) * 16 + (lane & 15);
        C[ct] = (f32x4){0.f, 0.f, 0.f, 0.f};
#pragma unroll
        for (int kt = 0; kt < 4; ++kt) {
            const int d2b = (kt * 16 + kg * 4) ^ ((col & 7) << 3);
            const uint4 w = *(const uint4*)&Wlds[col][d2b];
            H8 b;
            b.v[0] = u2h(w.x); b.v[1] = u2h(w.y);
            b.v[2] = u2h(w.z); b.v[3] = u2h(w.w);
            C[ct] = __builtin_amdgcn_mfma_f32_16x16x32_f16(
                        A[kt], __builtin_bit_cast(f16x8, b), C[ct], 0, 0, 0);
        }
    }

    // ---- epilogues ----
    if (m == 0) {
        float s0 = 0.f, s1 = 0.f, s2 = 0.f, s3 = 0.f;
#pragma unroll
        for (int ct = 0; ct < 4; ++ct) {
            const int col = (cg * 4 + ct) * 16 + (lane & 15);
            const float b1 = bo1[col];
            const float w2 = Wo2[col];
            s0 = fmaf(fmaxf(C[ct].x + b1, 0.f), w2, s0);
            s1 = fmaf(fmaxf(C[ct].y + b1, 0.f), w2, s1);
            s2 = fmaf(fmaxf(C[ct].z + b1, 0.f), w2, s2);
            s3 = fmaf(fmaxf(C[ct].w + b1, 0.f), w2, s3);
        }
#pragma unroll
        for (int off = 1; off <= 8; off <<= 1) {
            s0 += __shfl_xor(s0, off, 64);
            s1 += __shfl_xor(s1, off, 64);
            s2 += __shfl_xor(s2, off, 64);
            s3 += __shfl_xor(s3, off, 64);
        }
        if ((lane & 15) == 0) {
            const int rbase = rt * 16 + kg * 4;
            org_part[rbase + 0][cg] = s0;
            org_part[rbase + 1][cg] = s1;
            org_part[rbase + 2][cg] = s2;
            org_part[rbase + 3][cg] = s3;
        }
        __syncthreads();
        if (t < 32) {
            const float s = org_part[t][0] + org_part[t][1]
                          + org_part[t][2] + org_part[t][3] + bo2[0];
            organ_out[rb * 32 + t] = sigmoidf_(s);
        }
    } else if (m == 1) {
        // pi: row-major [row][hp], +be1
#pragma unroll
        for (int ct = 0; ct < 4; ++ct) {
            const int col = (cg * 4 + ct) * 16 + (lane & 15);
            const float bv = be1[col];
            float v0 = C[ct].x + bv, v1 = C[ct].y + bv;
            float v2 = C[ct].z + bv, v3 = C[ct].w + bv;
            const float p0 = __shfl_xor(v0, 1, 64);
            const float p1 = __shfl_xor(v1, 1, 64);
            const float p2 = __shfl_xor(v2, 1, 64);
            const float p3 = __shfl_xor(v3, 1, 64);
            if (!(lane & 1)) {
                const int hp = col >> 1;
                const size_t gr = (size_t)(rb * 32 + rt * 16 + kg * 4);
                pi_h[(gr + 0) * 128 + hp] = h2u(pkrtz(v0, p0));
                pi_h[(gr + 1) * 128 + hp] = h2u(pkrtz(v1, p1));
                pi_h[(gr + 2) * 128 + hp] = h2u(pkrtz(v2, p2));
                pi_h[(gr + 3) * 128 + hp] = h2u(pkrtz(v3, p3));
            }
        }
    } else {
        // pj: TRANSPOSED [hp][row]
#pragma unroll
        for (int ct = 0; ct < 4; ++ct) {
            const int col = (cg * 4 + ct) * 16 + (lane & 15);
            float v0 = C[ct].x, v1 = C[ct].y, v2 = C[ct].z, v3 = C[ct].w;
            const float p0 = __shfl_xor(v0, 1, 64);
            const float p1 = __shfl_xor(v1, 1, 64);
            const float p2 = __shfl_xor(v2, 1, 64);
            const float p3 = __shfl_xor(v3, 1, 64);
            if (!(lane & 1)) {
                const int hp = col >> 1;
                const size_t gr = (size_t)(rb * 32 + rt * 16 + kg * 4);
                pj_T[(size_t)hp * (BATCH * NN) + gr + 0] = h2u(pkrtz(v0, p0));
                pj_T[(size_t)hp * (BATCH * NN) + gr + 1] = h2u(pkrtz(v1, p1));
                pj_T[(size_t)hp * (BATCH * NN) + gr + 2] = h2u(pkrtz(v2, p2));
                pj_T[(size_t)hp * (BATCH * NN) + gr + 3] = h2u(pkrtz(v3, p3));
            }
        }
    }
}

// ---------------------------------------------------------------------------
// Kernel 2: fused edge head, reduction-free + SOFTWARE-PIPELINED pj.
// r15 structure (8i x 32j tile, 1024 blocks, lane=(ih,jl), per-lane acc,
// #pragma unroll 1 hc-loop, demand-driven launch bounds — VGPR-spill-free,
// 39.3 us total). One change: the 8 global pj loads (the only global memory
// in the loop, ~200-400 cy L2 latency that unroll-1 serialized against each
// iteration's 136-cy compute) are PREFETCHED one iteration ahead. The
// s_waitcnt for iteration hc+4's loads lands after iteration hc's full
// compute body -> latency hidden. +8-16 VGPR live (headroom to 128 at
// 4 waves/SIMD).
// ---------------------------------------------------------------------------
__global__ __launch_bounds__(256) void edge_kernel(
    const float* __restrict__ E,      // (N,N,9)
    const int*   __restrict__ mask,   // (N,N)
    const float* __restrict__ We_e,   // (9,256)
    const float* __restrict__ We2,    // (256,1)
    const float* __restrict__ be2,    // (1)
    const uint32_t* __restrict__ pi_h,  // (B*N,128) half2 rows
    const uint32_t* __restrict__ pj_T,  // (128,B*N) half2 transposed
    float* __restrict__ edge_out)     // (B,N,N)
{
    __shared__ __align__(16) uint32_t E_s[8][32][12];       // dup'd h2v, 12 KiB
    __shared__ __align__(16) uint32_t wee_s[EDGE_DIM][128]; // 4.5 KiB
    __shared__ __align__(16) uint32_t we2_s[128];           // 0.5 KiB
    __shared__ __align__(16) uint32_t pi_s[BATCH][8][128];  // 8 KiB

    const int t    = threadIdx.x;
    const int lane = t & 63;
    const int w    = t >> 6;           // wave 0..3 -> i-pair {2w, 2w+1}
    const int bi   = blockIdx.x;
    const int i0   = (bi >> 4) * 8;    // 64 i-blocks
    const int j0   = (bi & 15) * 32;   // 16 j-blocks

    const int jl = lane & 31;
    const int ih = lane >> 5;          // which i of the pair
    const int il = 2 * w + ih;         // local i row 0..7

    // ---- stage E tile (8 rows x 32 j x 9 d, dup'd f16 pairs) ----
#pragma unroll
    for (int ii = 0; ii < 8; ++ii) {
        const float* src = &E[((size_t)(i0 + ii) * NN + j0) * EDGE_DIM];
        for (int idx = t; idx < 32 * EDGE_DIM; idx += 256) {
            const int jj = idx / 9;
            const int d  = idx - jj * 9;
            const float e = src[idx];
            E_s[ii][jj][d] = h2u(pkrtz(e, e));
        }
    }
    // ---- stage We_e as h2v [d][h2] ----
    for (int idx = t; idx < EDGE_DIM * 128; idx += 256) {
        const int d  = idx >> 7;
        const int h2 = idx & 127;
        wee_s[d][h2] = h2u(pkrtz(We_e[d * 256 + 2 * h2], We_e[d * 256 + 2 * h2 + 1]));
    }
    // ---- stage We2 as h2v ----
    if (t < 128) we2_s[t] = h2u(pkrtz(We2[2 * t], We2[2 * t + 1]));
    // ---- stage pi rows: 2 b x 8 i x 128 uint32 = 512 uint4, 2/thread ----
#pragma unroll
    for (int k = 0; k < 2; ++k) {
        const int idx = t + k * 256;          // 0..511
        const int r16 = idx >> 5;             // row 0..15
        const int c4  = idx & 31;             // uint4 col
        const int b   = r16 >> 3;
        const int ii  = r16 & 7;
        const uint4 v = *(const uint4*)&pi_h[(size_t)(b * NN + i0 + ii) * 128 + c4 * 4];
        *(uint4*)&pi_s[b][ii][c4 * 4] = v;
    }
    __syncthreads();

    // ---- per-lane E registers: 1 i x 9 d ----
    h2v e[9];
    {
        const uint32_t* r0 = &E_s[il][jl][0];
        const uint4 a0 = *(const uint4*)(r0);
        const uint4 b0 = *(const uint4*)(r0 + 4);
        e[0]=u2h(a0.x); e[1]=u2h(a0.y); e[2]=u2h(a0.z); e[3]=u2h(a0.w);
        e[4]=u2h(b0.x); e[5]=u2h(b0.y); e[6]=u2h(b0.z); e[7]=u2h(b0.w);
        e[8]=u2h(r0[8]);
    }

    float acc[2] = {0.f, 0.f};   // [b]

    const uint32_t* pjbase0 = pj_T + j0 + jl;              // b = 0
    const uint32_t* pjbase1 = pj_T + NN + j0 + jl;         // b = 1

    // ---- prefetch pj for hc = 0 ----
    uint32_t pjn0[4], pjn1[4];
#pragma unroll
    for (int k = 0; k < 4; ++k) {
        pjn0[k] = pjbase0[(size_t)k * (BATCH * NN)];
        pjn1[k] = pjbase1[(size_t)k * (BATCH * NN)];
    }

#pragma unroll 1
    for (int hc = 0; hc < 128; hc += 4) {
        // consume current prefetch
        uint32_t pjv0[4], pjv1[4];
#pragma unroll
        for (int k = 0; k < 4; ++k) { pjv0[k] = pjn0[k]; pjv1[k] = pjn1[k]; }

        // issue next iteration's pj loads BEFORE this iteration's compute
        if (hc < 124) {
#pragma unroll
            for (int k = 0; k < 4; ++k) {
                pjn0[k] = pjbase0[(size_t)(hc + 4 + k) * (BATCH * NN)];
                pjn1[k] = pjbase1[(size_t)(hc + 4 + k) * (BATCH * NN)];
            }
        }

        // broadcast operands (b128: wee -> we2 -> pi)
        uint4 wee4[EDGE_DIM];
#pragma unroll
        for (int d = 0; d < EDGE_DIM; ++d) wee4[d] = *(const uint4*)&wee_s[d][hc];
        const uint4 we24 = *(const uint4*)&we2_s[hc];
        uint4 pi4[2];   // [b], per-lane il (2-way broadcast across lane halves)
        pi4[0] = *(const uint4*)&pi_s[0][il][hc];
        pi4[1] = *(const uint4*)&pi_s[1][il][hc];

#pragma unroll
        for (int k = 0; k < 4; ++k) {
            const h2v w2k = u2h(el(we24, k));
            h2v pe = e[0] * u2h(el(wee4[0], k));
#pragma unroll
            for (int d = 1; d < EDGE_DIM; ++d) pe += e[d] * u2h(el(wee4[d], k));
            h2v t0 = relu2(pe + u2h(pjv0[k]) + u2h(el(pi4[0], k)));
            acc[0] = fdot2(t0, w2k, acc[0]);
            h2v t1 = relu2(pe + u2h(pjv1[k]) + u2h(el(pi4[1], k)));
            acc[1] = fdot2(t1, w2k, acc[1]);
        }
    }

    // ---- epilogue: 2 outputs per lane, coalesced stores ----
    const float b2 = be2[0];
    const int i = i0 + il;
    const float mv = (float)mask[(size_t)i * NN + j0 + jl];
#pragma unroll
    for (int b = 0; b < 2; ++b) {
        const float s = acc[b] + b2;
        edge_out[((size_t)b * NN + i) * NN + j0 + jl] = sigmoidf_(s) * mv;
    }
}

extern "C" void kernel_launch(void* const* d_in, const int* in_sizes, int n_in,
                              void* d_out, int out_size, void* d_ws, size_t ws_size,
                              hipStream_t stream) {
    const float* z    = (const float*)d_in[0];   // (B,N,128)
    const float* E    = (const float*)d_in[1];   // (N,N,9)
    const int*   mask = (const int*)  d_in[2];   // (N,N)
    const float* Wo1  = (const float*)d_in[3];
    const float* bo1  = (const float*)d_in[4];
    const float* Wo2  = (const float*)d_in[5];
    const float* bo2  = (const float*)d_in[6];
    const float* We_i = (const float*)d_in[7];
    const float* We_j = (const float*)d_in[8];
    const float* We_e = (const float*)d_in[9];
    const float* be1  = (const float*)d_in[10];
    const float* We2  = (const float*)d_in[11];
    const float* be2  = (const float*)d_in[12];

    float* out_organ = (float*)d_out;                 // (B,N) = 1024
    float* out_edge  = out_organ + BATCH * NN;        // (B,N,N)

    uint32_t* pi_h = (uint32_t*)d_ws;                        // (B*N,128) half2
    uint32_t* pj_T = pi_h + (size_t)BATCH * NN * (HIDDEN/2); // (128,B*N) half2

    hipLaunchKernelGGL(node_mfma_kernel,
                       dim3(32, 3), dim3(512), 0, stream,
                       z, Wo1, bo1, Wo2, bo2, We_i, We_j, be1,
                       out_organ, pi_h, pj_T);

    hipLaunchKernelGGL(edge_kernel,
                       dim3(64 * 16), dim3(256), 0, stream,
                       E, mask, We_e, We2, be2, pi_h, pj_T, out_edge);
}

// Round 17
// 39.439 us; speedup vs baseline: 1.0739x; 1.0739x over previous
//
#include <hip/hip_runtime.h>
#include <math.h>
#include <stdint.h>

#define D_MODEL 128
#define EDGE_DIM 9
#define HIDDEN 256
#define BATCH 2
#define NN 512

typedef _Float16 h2v    __attribute__((ext_vector_type(2)));
typedef __fp16   fp16x2 __attribute__((ext_vector_type(2)));
typedef _Float16 f16x8  __attribute__((ext_vector_type(8)));
typedef float    f32x4  __attribute__((ext_vector_type(4)));

struct H8 { h2v v[4]; };   // 16B = one MFMA A/B fragment

__device__ __forceinline__ uint32_t h2u(h2v v) { return __builtin_bit_cast(uint32_t, v); }
__device__ __forceinline__ h2v u2h(uint32_t u) { return __builtin_bit_cast(h2v, u); }
__device__ __forceinline__ h2v pkrtz(float a, float b) {
    return __builtin_bit_cast(h2v, __builtin_amdgcn_cvt_pkrtz(a, b));
}
__device__ __forceinline__ h2v relu2(h2v v) {
    h2v z = {(_Float16)0.0f, (_Float16)0.0f};
    return __builtin_elementwise_max(v, z);
}
__device__ __forceinline__ float fdot2(h2v a, h2v b, float c) {
    return __builtin_amdgcn_fdot2(__builtin_bit_cast(fp16x2, a),
                                  __builtin_bit_cast(fp16x2, b), c, false);
}
__device__ __forceinline__ float sigmoidf_(float x) { return 1.f / (1.f + expf(-x)); }
// uint4 element by unroll-constant index (folds to .x/.y/.z/.w)
__device__ __forceinline__ uint32_t el(const uint4& u, int k) {
    switch (k) { case 0: return u.x; case 1: return u.y; case 2: return u.z; default: return u.w; }
}

// ---------------------------------------------------------------------------
// Kernel 1 (MFMA): C = z @ W for one of {Wo1, We_i, We_j} per block.y.
// Round-12 version + one addition: block (rb==0, m==0) also converts
// We_e/We2 to packed-f16 in global workspace (wee_g[d*128+h2], we2_g[h2])
// for the edge kernel's scalar-path reads.
// ---------------------------------------------------------------------------
__global__ __launch_bounds__(512) void node_mfma_kernel(
    const float* __restrict__ z,      // (B*N, 128)
    const float* __restrict__ Wo1,    // (128,256)
    const float* __restrict__ bo1,    // (256)
    const float* __restrict__ Wo2,    // (256,1)
    const float* __restrict__ bo2,    // (1)
    const float* __restrict__ We_i,   // (128,256)
    const float* __restrict__ We_j,   // (128,256)
    const float* __restrict__ be1,    // (256)
    const float* __restrict__ We_e,   // (9,256)
    const float* __restrict__ We2,    // (256,1)
    float* __restrict__ organ_out,    // (B*N)
    uint32_t* __restrict__ pi_h,      // (B*N,128) half2 rows, includes +be1
    uint32_t* __restrict__ pj_T,      // (128,B*N) half2 TRANSPOSED
    uint32_t* __restrict__ wee_g,     // (9*128) half2
    uint32_t* __restrict__ we2_g)     // (128) half2
{
    __shared__ uint32_t Wlds[256][68];     // ~69.6 KiB, f16-pair, [h][d2^swz]
    __shared__ float org_part[32][4];

    const int t    = threadIdx.x;
    const int lane = t & 63;
    const int wave = t >> 6;
    const int rb   = blockIdx.x;           // row-block: rows 32*rb..32*rb+31
    const int m    = blockIdx.y;           // 0 = Wo1/organ, 1 = We_i/pi, 2 = We_j/pj

    const float* __restrict__ W = (m == 0) ? Wo1 : (m == 1) ? We_i : We_j;

    // ---- one block converts We_e/We2 to h2 workspace for the edge kernel ----
    if (m == 0 && rb == 0) {
        for (int idx = t; idx < EDGE_DIM * 128; idx += 512) {
            const int d  = idx >> 7;
            const int h2 = idx & 127;
            wee_g[idx] = h2u(pkrtz(We_e[d * 256 + 2 * h2], We_e[d * 256 + 2 * h2 + 1]));
        }
        if (t < 128) we2_g[t] = h2u(pkrtz(We2[2 * t], We2[2 * t + 1]));
    }

    // ---- stage W -> LDS f16, transposed, swizzled ----
    for (int idx = t; idx < 64 * 256; idx += 512) {
        const int d2 = idx >> 8;           // 0..63 (d-pair)
        const int h  = idx & 255;          // coalesced over h
        const float wlo = W[(2 * d2) * 256 + h];
        const float whi = W[(2 * d2 + 1) * 256 + h];
        Wlds[h][d2 ^ ((h & 7) << 3)] = h2u(pkrtz(wlo, whi));
    }

    // ---- A-frags straight from global ----
    const int rt = wave & 1;               // row-tile
    const int cg = wave >> 1;              // col-group (4 tiles of 16)
    const int kg = lane >> 4;              // k-subgroup
    const int row = rb * 32 + rt * 16 + (lane & 15);

    f16x8 A[4];
#pragma unroll
    for (int kt = 0; kt < 4; ++kt) {
        const float4 za = *(const float4*)&z[(size_t)row * 128 + kt * 32 + kg * 8];
        const float4 zb = *(const float4*)&z[(size_t)row * 128 + kt * 32 + kg * 8 + 4];
        H8 a;
        a.v[0] = pkrtz(za.x, za.y); a.v[1] = pkrtz(za.z, za.w);
        a.v[2] = pkrtz(zb.x, zb.y); a.v[3] = pkrtz(zb.z, zb.w);
        A[kt] = __builtin_bit_cast(f16x8, a);
    }

    __syncthreads();

    // ---- MFMA main: 4 col-tiles x 4 k-tiles ----
    f32x4 C[4];
#pragma unroll
    for (int ct = 0; ct < 4; ++ct) {
        const int col = (cg * 4 + ct) * 16 + (lane & 15);
        C[ct] = (f32x4){0.f, 0.f, 0.f, 0.f};
#pragma unroll
        for (int kt = 0; kt < 4; ++kt) {
            const int d2b = (kt * 16 + kg * 4) ^ ((col & 7) << 3);
            const uint4 w = *(const uint4*)&Wlds[col][d2b];
            H8 b;
            b.v[0] = u2h(w.x); b.v[1] = u2h(w.y);
            b.v[2] = u2h(w.z); b.v[3] = u2h(w.w);
            C[ct] = __builtin_amdgcn_mfma_f32_16x16x32_f16(
                        A[kt], __builtin_bit_cast(f16x8, b), C[ct], 0, 0, 0);
        }
    }

    // ---- epilogues ----
    if (m == 0) {
        float s0 = 0.f, s1 = 0.f, s2 = 0.f, s3 = 0.f;
#pragma unroll
        for (int ct = 0; ct < 4; ++ct) {
            const int col = (cg * 4 + ct) * 16 + (lane & 15);
            const float b1 = bo1[col];
            const float w2 = Wo2[col];
            s0 = fmaf(fmaxf(C[ct].x + b1, 0.f), w2, s0);
            s1 = fmaf(fmaxf(C[ct].y + b1, 0.f), w2, s1);
            s2 = fmaf(fmaxf(C[ct].z + b1, 0.f), w2, s2);
            s3 = fmaf(fmaxf(C[ct].w + b1, 0.f), w2, s3);
        }
#pragma unroll
        for (int off = 1; off <= 8; off <<= 1) {
            s0 += __shfl_xor(s0, off, 64);
            s1 += __shfl_xor(s1, off, 64);
            s2 += __shfl_xor(s2, off, 64);
            s3 += __shfl_xor(s3, off, 64);
        }
        if ((lane & 15) == 0) {
            const int rbase = rt * 16 + kg * 4;
            org_part[rbase + 0][cg] = s0;
            org_part[rbase + 1][cg] = s1;
            org_part[rbase + 2][cg] = s2;
            org_part[rbase + 3][cg] = s3;
        }
        __syncthreads();
        if (t < 32) {
            const float s = org_part[t][0] + org_part[t][1]
                          + org_part[t][2] + org_part[t][3] + bo2[0];
            organ_out[rb * 32 + t] = sigmoidf_(s);
        }
    } else if (m == 1) {
        // pi: row-major [row][hp], +be1
#pragma unroll
        for (int ct = 0; ct < 4; ++ct) {
            const int col = (cg * 4 + ct) * 16 + (lane & 15);
            const float bv = be1[col];
            float v0 = C[ct].x + bv, v1 = C[ct].y + bv;
            float v2 = C[ct].z + bv, v3 = C[ct].w + bv;
            const float p0 = __shfl_xor(v0, 1, 64);
            const float p1 = __shfl_xor(v1, 1, 64);
            const float p2 = __shfl_xor(v2, 1, 64);
            const float p3 = __shfl_xor(v3, 1, 64);
            if (!(lane & 1)) {
                const int hp = col >> 1;
                const size_t gr = (size_t)(rb * 32 + rt * 16 + kg * 4);
                pi_h[(gr + 0) * 128 + hp] = h2u(pkrtz(v0, p0));
                pi_h[(gr + 1) * 128 + hp] = h2u(pkrtz(v1, p1));
                pi_h[(gr + 2) * 128 + hp] = h2u(pkrtz(v2, p2));
                pi_h[(gr + 3) * 128 + hp] = h2u(pkrtz(v3, p3));
            }
        }
    } else {
        // pj: TRANSPOSED [hp][row]
#pragma unroll
        for (int ct = 0; ct < 4; ++ct) {
            const int col = (cg * 4 + ct) * 16 + (lane & 15);
            float v0 = C[ct].x, v1 = C[ct].y, v2 = C[ct].z, v3 = C[ct].w;
            const float p0 = __shfl_xor(v0, 1, 64);
            const float p1 = __shfl_xor(v1, 1, 64);
            const float p2 = __shfl_xor(v2, 1, 64);
            const float p3 = __shfl_xor(v3, 1, 64);
            if (!(lane & 1)) {
                const int hp = col >> 1;
                const size_t gr = (size_t)(rb * 32 + rt * 16 + kg * 4);
                pj_T[(size_t)hp * (BATCH * NN) + gr + 0] = h2u(pkrtz(v0, p0));
                pj_T[(size_t)hp * (BATCH * NN) + gr + 1] = h2u(pkrtz(v1, p1));
                pj_T[(size_t)hp * (BATCH * NN) + gr + 2] = h2u(pkrtz(v2, p2));
                pj_T[(size_t)hp * (BATCH * NN) + gr + 3] = h2u(pkrtz(v3, p3));
            }
        }
    }
}

// ---------------------------------------------------------------------------
// Kernel 2: fused edge head, reduction-free + SCALAR-PATH weights.
// r15 structure (8i x 32j, 1024 blocks, lane=(ih,jl), per-lane acc,
// #pragma unroll 1, demand-driven bounds) with the LDS-pipe fix: wee/we2
// were 10 of 12 per-iteration LDS b128 broadcasts, block-redundant x4 waves
// -> r16 counters showed LDS-pipe ~4x oversubscribed (VALUBusy 45%).
// Now read from global h2 workspace at WAVE-UNIFORM addresses (const
// __restrict__, uniform index) -> scalar loads / 1-line vector loads on the
// constant-cache path; 5 KB total, L2-hot. LDS keeps only E (one-time) and
// pi (2 b128/iter).
// ---------------------------------------------------------------------------
__global__ __launch_bounds__(256) void edge_kernel(
    const float* __restrict__ E,      // (N,N,9)
    const int*   __restrict__ mask,   // (N,N)
    const uint32_t* __restrict__ wee_g, // (9*128) half2
    const uint32_t* __restrict__ we2_g, // (128) half2
    const float* __restrict__ be2,    // (1)
    const uint32_t* __restrict__ pi_h,  // (B*N,128) half2 rows
    const uint32_t* __restrict__ pj_T,  // (128,B*N) half2 transposed
    float* __restrict__ edge_out)     // (B,N,N)
{
    __shared__ __align__(16) uint32_t E_s[8][32][12];       // dup'd h2v, 12 KiB
    __shared__ __align__(16) uint32_t pi_s[BATCH][8][128];  // 8 KiB

    const int t    = threadIdx.x;
    const int lane = t & 63;
    const int w    = t >> 6;           // wave 0..3 -> i-pair {2w, 2w+1}
    const int bi   = blockIdx.x;
    const int i0   = (bi >> 4) * 8;    // 64 i-blocks
    const int j0   = (bi & 15) * 32;   // 16 j-blocks

    const int jl = lane & 31;
    const int ih = lane >> 5;          // which i of the pair
    const int il = 2 * w + ih;         // local i row 0..7

    // ---- stage E tile (8 rows x 32 j x 9 d, dup'd f16 pairs) ----
#pragma unroll
    for (int ii = 0; ii < 8; ++ii) {
        const float* src = &E[((size_t)(i0 + ii) * NN + j0) * EDGE_DIM];
        for (int idx = t; idx < 32 * EDGE_DIM; idx += 256) {
            const int jj = idx / 9;
            const int d  = idx - jj * 9;
            const float e = src[idx];
            E_s[ii][jj][d] = h2u(pkrtz(e, e));
        }
    }
    // ---- stage pi rows: 2 b x 8 i x 128 uint32 = 512 uint4, 2/thread ----
#pragma unroll
    for (int k = 0; k < 2; ++k) {
        const int idx = t + k * 256;          // 0..511
        const int r16 = idx >> 5;             // row 0..15
        const int c4  = idx & 31;             // uint4 col
        const int b   = r16 >> 3;
        const int ii  = r16 & 7;
        const uint4 v = *(const uint4*)&pi_h[(size_t)(b * NN + i0 + ii) * 128 + c4 * 4];
        *(uint4*)&pi_s[b][ii][c4 * 4] = v;
    }
    __syncthreads();

    // ---- per-lane E registers: 1 i x 9 d ----
    h2v e[9];
    {
        const uint32_t* r0 = &E_s[il][jl][0];
        const uint4 a0 = *(const uint4*)(r0);
        const uint4 b0 = *(const uint4*)(r0 + 4);
        e[0]=u2h(a0.x); e[1]=u2h(a0.y); e[2]=u2h(a0.z); e[3]=u2h(a0.w);
        e[4]=u2h(b0.x); e[5]=u2h(b0.y); e[6]=u2h(b0.z); e[7]=u2h(b0.w);
        e[8]=u2h(r0[8]);
    }

    float acc[2] = {0.f, 0.f};   // [b]

    const uint32_t* pjbase0 = pj_T + j0 + jl;              // b = 0
    const uint32_t* pjbase1 = pj_T + NN + j0 + jl;         // b = 1
    const uint4* wee_g4 = (const uint4*)wee_g;             // [9][32] uint4
    const uint4* we2_g4 = (const uint4*)we2_g;             // [32] uint4

#pragma unroll 1
    for (int hc = 0; hc < 128; hc += 4) {
        const int c4 = hc >> 2;
        // wave-uniform weight chunks -> scalar path (s_load / 1-line fetch)
        uint4 wee4[EDGE_DIM];
#pragma unroll
        for (int d = 0; d < EDGE_DIM; ++d) wee4[d] = wee_g4[d * 32 + c4];
        const uint4 we24 = we2_g4[c4];
        // LDS: pi only (2 b128, 2-way broadcast across lane halves)
        uint4 pi4[2];   // [b]
        pi4[0] = *(const uint4*)&pi_s[0][il][hc];
        pi4[1] = *(const uint4*)&pi_s[1][il][hc];
        // coalesced per-lane pj (r15 pattern, no manual prefetch)
        uint32_t pjv0[4], pjv1[4];
#pragma unroll
        for (int k = 0; k < 4; ++k) {
            pjv0[k] = pjbase0[(size_t)(hc + k) * (BATCH * NN)];
            pjv1[k] = pjbase1[(size_t)(hc + k) * (BATCH * NN)];
        }

#pragma unroll
        for (int k = 0; k < 4; ++k) {
            const h2v w2k = u2h(el(we24, k));
            h2v pe = e[0] * u2h(el(wee4[0], k));
#pragma unroll
            for (int d = 1; d < EDGE_DIM; ++d) pe += e[d] * u2h(el(wee4[d], k));
            h2v t0 = relu2(pe + u2h(pjv0[k]) + u2h(el(pi4[0], k)));
            acc[0] = fdot2(t0, w2k, acc[0]);
            h2v t1 = relu2(pe + u2h(pjv1[k]) + u2h(el(pi4[1], k)));
            acc[1] = fdot2(t1, w2k, acc[1]);
        }
    }

    // ---- epilogue: 2 outputs per lane, coalesced stores ----
    const float b2 = be2[0];
    const int i = i0 + il;
    const float mv = (float)mask[(size_t)i * NN + j0 + jl];
#pragma unroll
    for (int b = 0; b < 2; ++b) {
        const float s = acc[b] + b2;
        edge_out[((size_t)b * NN + i) * NN + j0 + jl] = sigmoidf_(s) * mv;
    }
}

extern "C" void kernel_launch(void* const* d_in, const int* in_sizes, int n_in,
                              void* d_out, int out_size, void* d_ws, size_t ws_size,
                              hipStream_t stream) {
    const float* z    = (const float*)d_in[0];   // (B,N,128)
    const float* E    = (const float*)d_in[1];   // (N,N,9)
    const int*   mask = (const int*)  d_in[2];   // (N,N)
    const float* Wo1  = (const float*)d_in[3];
    const float* bo1  = (const float*)d_in[4];
    const float* Wo2  = (const float*)d_in[5];
    const float* bo2  = (const float*)d_in[6];
    const float* We_i = (const float*)d_in[7];
    const float* We_j = (const float*)d_in[8];
    const float* We_e = (const float*)d_in[9];
    const float* be1  = (const float*)d_in[10];
    const float* We2  = (const float*)d_in[11];
    const float* be2  = (const float*)d_in[12];

    float* out_organ = (float*)d_out;                 // (B,N) = 1024
    float* out_edge  = out_organ + BATCH * NN;        // (B,N,N)

    uint32_t* pi_h  = (uint32_t*)d_ws;                        // (B*N,128) half2
    uint32_t* pj_T  = pi_h + (size_t)BATCH * NN * (HIDDEN/2); // (128,B*N) half2
    uint32_t* wee_g = pj_T + (size_t)BATCH * NN * (HIDDEN/2); // (9*128) half2
    uint32_t* we2_g = wee_g + EDGE_DIM * 128;                 // (128) half2

    hipLaunchKernelGGL(node_mfma_kernel,
                       dim3(32, 3), dim3(512), 0, stream,
                       z, Wo1, bo1, Wo2, bo2, We_i, We_j, be1, We_e, We2,
                       out_organ, pi_h, pj_T, wee_g, we2_g);

    hipLaunchKernelGGL(edge_kernel,
                       dim3(64 * 16), dim3(256), 0, stream,
                       E, mask, wee_g, we2_g, be2, pi_h, pj_T, out_edge);
}

// Round 18
// 36.885 us; speedup vs baseline: 1.1483x; 1.0692x over previous
//
#include <hip/hip_runtime.h>
#include <math.h>
#include <stdint.h>

#define D_MODEL 128
#define EDGE_DIM 9
#define HIDDEN 256
#define BATCH 2
#define NN 512

typedef _Float16 h2v    __attribute__((ext_vector_type(2)));
typedef __fp16   fp16x2 __attribute__((ext_vector_type(2)));
typedef _Float16 f16x8  __attribute__((ext_vector_type(8)));
typedef float    f32x4  __attribute__((ext_vector_type(4)));

struct H8 { h2v v[4]; };   // 16B = one MFMA A/B fragment

__device__ __forceinline__ uint32_t h2u(h2v v) { return __builtin_bit_cast(uint32_t, v); }
__device__ __forceinline__ h2v u2h(uint32_t u) { return __builtin_bit_cast(h2v, u); }
__device__ __forceinline__ h2v pkrtz(float a, float b) {
    return __builtin_bit_cast(h2v, __builtin_amdgcn_cvt_pkrtz(a, b));
}
__device__ __forceinline__ h2v relu2(h2v v) {
    h2v z = {(_Float16)0.0f, (_Float16)0.0f};
    return __builtin_elementwise_max(v, z);
}
__device__ __forceinline__ float fdot2(h2v a, h2v b, float c) {
    return __builtin_amdgcn_fdot2(__builtin_bit_cast(fp16x2, a),
                                  __builtin_bit_cast(fp16x2, b), c, false);
}
__device__ __forceinline__ float sigmoidf_(float x) { return 1.f / (1.f + expf(-x)); }
// uint4 element by unroll-constant index (folds to .x/.y/.z/.w)
__device__ __forceinline__ uint32_t el(const uint4& u, int k) {
    switch (k) { case 0: return u.x; case 1: return u.y; case 2: return u.z; default: return u.w; }
}

// ---------------------------------------------------------------------------
// Kernel 1 (MFMA): C = z @ W for one of {Wo1, We_i, We_j} per block.y.
// Round-12 version; m==2 (pj) now stores PACKED-GROUP layout:
// pj_q[((hp>>2)*1024 + row)*4 + (hp&3)] (uint32 scatter, same cost as the
// old transpose) so the edge kernel reads each 4-hp group of a row as ONE
// uint4: ((uint4*)pj_q)[(hp>>2)*1024 + row].
// ---------------------------------------------------------------------------
__global__ __launch_bounds__(512) void node_mfma_kernel(
    const float* __restrict__ z,      // (B*N, 128)
    const float* __restrict__ Wo1,    // (128,256)
    const float* __restrict__ bo1,    // (256)
    const float* __restrict__ Wo2,    // (256,1)
    const float* __restrict__ bo2,    // (1)
    const float* __restrict__ We_i,   // (128,256)
    const float* __restrict__ We_j,   // (128,256)
    const float* __restrict__ be1,    // (256)
    float* __restrict__ organ_out,    // (B*N)
    uint32_t* __restrict__ pi_h,      // (B*N,128) half2 rows, includes +be1
    uint32_t* __restrict__ pj_q)      // (32 groups,1024 rows) uint4-packed
{
    __shared__ uint32_t Wlds[256][68];     // ~69.6 KiB, f16-pair, [h][d2^swz]
    __shared__ float org_part[32][4];

    const int t    = threadIdx.x;
    const int lane = t & 63;
    const int wave = t >> 6;
    const int rb   = blockIdx.x;           // row-block: rows 32*rb..32*rb+31
    const int m    = blockIdx.y;           // 0 = Wo1/organ, 1 = We_i/pi, 2 = We_j/pj

    const float* __restrict__ W = (m == 0) ? Wo1 : (m == 1) ? We_i : We_j;

    // ---- stage W -> LDS f16, transposed, swizzled ----
    for (int idx = t; idx < 64 * 256; idx += 512) {
        const int d2 = idx >> 8;           // 0..63 (d-pair)
        const int h  = idx & 255;          // coalesced over h
        const float wlo = W[(2 * d2) * 256 + h];
        const float whi = W[(2 * d2 + 1) * 256 + h];
        Wlds[h][d2 ^ ((h & 7) << 3)] = h2u(pkrtz(wlo, whi));
    }

    // ---- A-frags straight from global ----
    const int rt = wave & 1;               // row-tile
    const int cg = wave >> 1;              // col-group (4 tiles of 16)
    const int kg = lane >> 4;              // k-subgroup
    const int row = rb * 32 + rt * 16 + (lane & 15);

    f16x8 A[4];
#pragma unroll
    for (int kt = 0; kt < 4; ++kt) {
        const float4 za = *(const float4*)&z[(size_t)row * 128 + kt * 32 + kg * 8];
        const float4 zb = *(const float4*)&z[(size_t)row * 128 + kt * 32 + kg * 8 + 4];
        H8 a;
        a.v[0] = pkrtz(za.x, za.y); a.v[1] = pkrtz(za.z, za.w);
        a.v[2] = pkrtz(zb.x, zb.y); a.v[3] = pkrtz(zb.z, zb.w);
        A[kt] = __builtin_bit_cast(f16x8, a);
    }

    __syncthreads();

    // ---- MFMA main: 4 col-tiles x 4 k-tiles ----
    f32x4 C[4];
#pragma unroll
    for (int ct = 0; ct < 4; ++ct) {
        const int col = (cg * 4 + ct) * 16 + (lane & 15);
        C[ct] = (f32x4){0.f, 0.f, 0.f, 0.f};
#pragma unroll
        for (int kt = 0; kt < 4; ++kt) {
            const int d2b = (kt * 16 + kg * 4) ^ ((col & 7) << 3);
            const uint4 w = *(const uint4*)&Wlds[col][d2b];
            H8 b;
            b.v[0] = u2h(w.x); b.v[1] = u2h(w.y);
            b.v[2] = u2h(w.z); b.v[3] = u2h(w.w);
            C[ct] = __builtin_amdgcn_mfma_f32_16x16x32_f16(
                        A[kt], __builtin_bit_cast(f16x8, b), C[ct], 0, 0, 0);
        }
    }

    // ---- epilogues ----
    if (m == 0) {
        float s0 = 0.f, s1 = 0.f, s2 = 0.f, s3 = 0.f;
#pragma unroll
        for (int ct = 0; ct < 4; ++ct) {
            const int col = (cg * 4 + ct) * 16 + (lane & 15);
            const float b1 = bo1[col];
            const float w2 = Wo2[col];
            s0 = fmaf(fmaxf(C[ct].x + b1, 0.f), w2, s0);
            s1 = fmaf(fmaxf(C[ct].y + b1, 0.f), w2, s1);
            s2 = fmaf(fmaxf(C[ct].z + b1, 0.f), w2, s2);
            s3 = fmaf(fmaxf(C[ct].w + b1, 0.f), w2, s3);
        }
#pragma unroll
        for (int off = 1; off <= 8; off <<= 1) {
            s0 += __shfl_xor(s0, off, 64);
            s1 += __shfl_xor(s1, off, 64);
            s2 += __shfl_xor(s2, off, 64);
            s3 += __shfl_xor(s3, off, 64);
        }
        if ((lane & 15) == 0) {
            const int rbase = rt * 16 + kg * 4;
            org_part[rbase + 0][cg] = s0;
            org_part[rbase + 1][cg] = s1;
            org_part[rbase + 2][cg] = s2;
            org_part[rbase + 3][cg] = s3;
        }
        __syncthreads();
        if (t < 32) {
            const float s = org_part[t][0] + org_part[t][1]
                          + org_part[t][2] + org_part[t][3] + bo2[0];
            organ_out[rb * 32 + t] = sigmoidf_(s);
        }
    } else if (m == 1) {
        // pi: row-major [row][hp], +be1
#pragma unroll
        for (int ct = 0; ct < 4; ++ct) {
            const int col = (cg * 4 + ct) * 16 + (lane & 15);
            const float bv = be1[col];
            float v0 = C[ct].x + bv, v1 = C[ct].y + bv;
            float v2 = C[ct].z + bv, v3 = C[ct].w + bv;
            const float p0 = __shfl_xor(v0, 1, 64);
            const float p1 = __shfl_xor(v1, 1, 64);
            const float p2 = __shfl_xor(v2, 1, 64);
            const float p3 = __shfl_xor(v3, 1, 64);
            if (!(lane & 1)) {
                const int hp = col >> 1;
                const size_t gr = (size_t)(rb * 32 + rt * 16 + kg * 4);
                pi_h[(gr + 0) * 128 + hp] = h2u(pkrtz(v0, p0));
                pi_h[(gr + 1) * 128 + hp] = h2u(pkrtz(v1, p1));
                pi_h[(gr + 2) * 128 + hp] = h2u(pkrtz(v2, p2));
                pi_h[(gr + 3) * 128 + hp] = h2u(pkrtz(v3, p3));
            }
        }
    } else {
        // pj: packed-group layout [hp>>2][row][hp&3]
#pragma unroll
        for (int ct = 0; ct < 4; ++ct) {
            const int col = (cg * 4 + ct) * 16 + (lane & 15);
            float v0 = C[ct].x, v1 = C[ct].y, v2 = C[ct].z, v3 = C[ct].w;
            const float p0 = __shfl_xor(v0, 1, 64);
            const float p1 = __shfl_xor(v1, 1, 64);
            const float p2 = __shfl_xor(v2, 1, 64);
            const float p3 = __shfl_xor(v3, 1, 64);
            if (!(lane & 1)) {
                const int hp = col >> 1;
                const size_t gr = (size_t)(rb * 32 + rt * 16 + kg * 4);
                const size_t gbase = (size_t)(hp >> 2) * 1024;
                const int    sub   = hp & 3;
                pj_q[(gbase + gr + 0) * 4 + sub] = h2u(pkrtz(v0, p0));
                pj_q[(gbase + gr + 1) * 4 + sub] = h2u(pkrtz(v1, p1));
                pj_q[(gbase + gr + 2) * 4 + sub] = h2u(pkrtz(v2, p2));
                pj_q[(gbase + gr + 3) * 4 + sub] = h2u(pkrtz(v3, p3));
            }
        }
    }
}

// ---------------------------------------------------------------------------
// Kernel 2: fused edge head, reduction-free + WIDE pj loads.
// r15 structure (8i x 32j, 1024 blocks, lane=(ih,jl), per-lane acc,
// weights in LDS broadcast, #pragma unroll 1, demand-driven bounds).
// Fix for the VMEM-pipe bottleneck (r15/r17 both plateaued ~39.3 with
// 8 global_load_dword pj per iter ~= 512 TA-cy/round vs 272 VALU-cy):
// pj re-laid out as uint4 hp-groups per row -> ONE global b128 per b per
// iter (2 VMEM instrs, lanes 0-31 contiguous 512B, upper half broadcast).
// Per-iter traffic: 10 LDS broadcast (weights) + 2 LDS (pi) + 2 VMEM (pj).
// ---------------------------------------------------------------------------
__global__ __launch_bounds__(256) void edge_kernel(
    const float* __restrict__ E,      // (N,N,9)
    const int*   __restrict__ mask,   // (N,N)
    const float* __restrict__ We_e,   // (9,256)
    const float* __restrict__ We2,    // (256,1)
    const float* __restrict__ be2,    // (1)
    const uint32_t* __restrict__ pi_h,  // (B*N,128) half2 rows
    const uint32_t* __restrict__ pj_q,  // (32,1024) uint4-packed
    float* __restrict__ edge_out)     // (B,N,N)
{
    __shared__ __align__(16) uint32_t E_s[8][32][12];       // dup'd h2v, 12 KiB
    __shared__ __align__(16) uint32_t wee_s[EDGE_DIM][128]; // 4.5 KiB
    __shared__ __align__(16) uint32_t we2_s[128];           // 0.5 KiB
    __shared__ __align__(16) uint32_t pi_s[BATCH][8][128];  // 8 KiB

    const int t    = threadIdx.x;
    const int lane = t & 63;
    const int w    = t >> 6;           // wave 0..3 -> i-pair {2w, 2w+1}
    const int bi   = blockIdx.x;
    const int i0   = (bi >> 4) * 8;    // 64 i-blocks
    const int j0   = (bi & 15) * 32;   // 16 j-blocks

    const int jl = lane & 31;
    const int ih = lane >> 5;          // which i of the pair
    const int il = 2 * w + ih;         // local i row 0..7

    // ---- stage E tile (8 rows x 32 j x 9 d, dup'd f16 pairs) ----
#pragma unroll
    for (int ii = 0; ii < 8; ++ii) {
        const float* src = &E[((size_t)(i0 + ii) * NN + j0) * EDGE_DIM];
        for (int idx = t; idx < 32 * EDGE_DIM; idx += 256) {
            const int jj = idx / 9;
            const int d  = idx - jj * 9;
            const float e = src[idx];
            E_s[ii][jj][d] = h2u(pkrtz(e, e));
        }
    }
    // ---- stage We_e as h2v [d][h2] ----
    for (int idx = t; idx < EDGE_DIM * 128; idx += 256) {
        const int d  = idx >> 7;
        const int h2 = idx & 127;
        wee_s[d][h2] = h2u(pkrtz(We_e[d * 256 + 2 * h2], We_e[d * 256 + 2 * h2 + 1]));
    }
    // ---- stage We2 as h2v ----
    if (t < 128) we2_s[t] = h2u(pkrtz(We2[2 * t], We2[2 * t + 1]));
    // ---- stage pi rows: 2 b x 8 i x 128 uint32 = 512 uint4, 2/thread ----
#pragma unroll
    for (int k = 0; k < 2; ++k) {
        const int idx = t + k * 256;          // 0..511
        const int r16 = idx >> 5;             // row 0..15
        const int c4  = idx & 31;             // uint4 col
        const int b   = r16 >> 3;
        const int ii  = r16 & 7;
        const uint4 v = *(const uint4*)&pi_h[(size_t)(b * NN + i0 + ii) * 128 + c4 * 4];
        *(uint4*)&pi_s[b][ii][c4 * 4] = v;
    }
    __syncthreads();

    // ---- per-lane E registers: 1 i x 9 d ----
    h2v e[9];
    {
        const uint32_t* r0 = &E_s[il][jl][0];
        const uint4 a0 = *(const uint4*)(r0);
        const uint4 b0 = *(const uint4*)(r0 + 4);
        e[0]=u2h(a0.x); e[1]=u2h(a0.y); e[2]=u2h(a0.z); e[3]=u2h(a0.w);
        e[4]=u2h(b0.x); e[5]=u2h(b0.y); e[6]=u2h(b0.z); e[7]=u2h(b0.w);
        e[8]=u2h(r0[8]);
    }

    float acc[2] = {0.f, 0.f};   // [b]

    const uint4* __restrict__ pjQ = (const uint4*)pj_q;   // [32][1024]
    const int jrow = j0 + jl;

#pragma unroll 1
    for (int hc = 0; hc < 128; hc += 4) {
        // broadcast weights (LDS, wave-uniform address)
        uint4 wee4[EDGE_DIM];
#pragma unroll
        for (int d = 0; d < EDGE_DIM; ++d) wee4[d] = *(const uint4*)&wee_s[d][hc];
        const uint4 we24 = *(const uint4*)&we2_s[hc];
        // pi (LDS, 2-way broadcast across lane halves)
        uint4 pi4[2];
        pi4[0] = *(const uint4*)&pi_s[0][il][hc];
        pi4[1] = *(const uint4*)&pi_s[1][il][hc];
        // pj: ONE b128 per batch (coalesced: lanes 0-31 contiguous 512B)
        const int g = hc >> 2;
        const uint4 pj40 = pjQ[g * 1024 + jrow];          // b = 0
        const uint4 pj41 = pjQ[g * 1024 + NN + jrow];     // b = 1

#pragma unroll
        for (int k = 0; k < 4; ++k) {
            const h2v w2k = u2h(el(we24, k));
            h2v pe = e[0] * u2h(el(wee4[0], k));
#pragma unroll
            for (int d = 1; d < EDGE_DIM; ++d) pe += e[d] * u2h(el(wee4[d], k));
            h2v t0 = relu2(pe + u2h(el(pj40, k)) + u2h(el(pi4[0], k)));
            acc[0] = fdot2(t0, w2k, acc[0]);
            h2v t1 = relu2(pe + u2h(el(pj41, k)) + u2h(el(pi4[1], k)));
            acc[1] = fdot2(t1, w2k, acc[1]);
        }
    }

    // ---- epilogue: 2 outputs per lane, coalesced stores ----
    const float b2 = be2[0];
    const int i = i0 + il;
    const float mv = (float)mask[(size_t)i * NN + j0 + jl];
#pragma unroll
    for (int b = 0; b < 2; ++b) {
        const float s = acc[b] + b2;
        edge_out[((size_t)b * NN + i) * NN + j0 + jl] = sigmoidf_(s) * mv;
    }
}

extern "C" void kernel_launch(void* const* d_in, const int* in_sizes, int n_in,
                              void* d_out, int out_size, void* d_ws, size_t ws_size,
                              hipStream_t stream) {
    const float* z    = (const float*)d_in[0];   // (B,N,128)
    const float* E    = (const float*)d_in[1];   // (N,N,9)
    const int*   mask = (const int*)  d_in[2];   // (N,N)
    const float* Wo1  = (const float*)d_in[3];
    const float* bo1  = (const float*)d_in[4];
    const float* Wo2  = (const float*)d_in[5];
    const float* bo2  = (const float*)d_in[6];
    const float* We_i = (const float*)d_in[7];
    const float* We_j = (const float*)d_in[8];
    const float* We_e = (const float*)d_in[9];
    const float* be1  = (const float*)d_in[10];
    const float* We2  = (const float*)d_in[11];
    const float* be2  = (const float*)d_in[12];

    float* out_organ = (float*)d_out;                 // (B,N) = 1024
    float* out_edge  = out_organ + BATCH * NN;        // (B,N,N)

    uint32_t* pi_h = (uint32_t*)d_ws;                        // (B*N,128) half2
    uint32_t* pj_q = pi_h + (size_t)BATCH * NN * (HIDDEN/2); // (32,1024) uint4-packed

    hipLaunchKernelGGL(node_mfma_kernel,
                       dim3(32, 3), dim3(512), 0, stream,
                       z, Wo1, bo1, Wo2, bo2, We_i, We_j, be1,
                       out_organ, pi_h, pj_q);

    hipLaunchKernelGGL(edge_kernel,
                       dim3(64 * 16), dim3(256), 0, stream,
                       E, mask, We_e, We2, be2, pi_h, pj_q, out_edge);
}